// Round 6
// baseline (33513.586 us; speedup 1.0000x reference)
//
#include <hip/hip_runtime.h>

typedef unsigned short u16;
typedef unsigned int u32;
typedef __bf16 bf16x8 __attribute__((ext_vector_type(8)));
typedef float f32x4 __attribute__((ext_vector_type(4)));
typedef float f32x2 __attribute__((ext_vector_type(2)));

#define YD 32
#define ZD 64
#define HD 256
#define RD 256
#define TSTEPS 199   // T-1 scan steps
#define BB 2048
#define MROWS 64     // batch rows per block
#define NBLK 32      // 2048/64
#define NTHR 1024    // 16 waves
#define CATS 388     // [x(32)|y(32)|z(64)|h(256)] + 4 pad
#define HBS  260     // 256 + 4 pad
#define HES  132     // [m|s](128) + 4 pad

// bf16 weight layout offsets inside d_ws (element units, (N,K) row-major, K contiguous)
enum : int {
  OFF_ENC_W1 = 0,        // 256x320
  OFF_ENC_W2 = 81920,    // 256x256
  OFF_ENC_H  = 147456,   // [enc_mw;enc_sw] 128x256
  OFF_PRI_W1 = 180224,   // 256x288
  OFF_PRI_W2 = 253952,   // 256x256
  OFF_PRI_H  = 319488,   // [pri_mw;pri_sw] 128x256
  OFF_DEC_W1 = 352256,   // 256x352
  OFF_DEC_W2 = 442368,   // 256x256
  OFF_DEC_H  = 507904,   // [dec_mw;dec_sw] 64x256
  OFF_GWIH   = 524288,   // 768x96
  OFF_GWHH   = 598016,   // 768x256
};

__device__ __forceinline__ u16 f2bf(float f) {
  u32 u = __float_as_uint(f);
  u += 0x7fffu + ((u >> 16) & 1u);   // RTNE
  return (u16)(u >> 16);
}
__device__ __forceinline__ float bf2f(u16 b) {
  return __uint_as_float((u32)b << 16);
}
__device__ __forceinline__ float softplus_f(float x) {
  float l = __logf(1.f + __expf(-fabsf(x)));
  return x > 0.f ? x + l : l;
}
__device__ __forceinline__ float sigmoid_f(float x) {
  return __builtin_amdgcn_rcpf(1.f + __expf(-x));
}
__device__ __forceinline__ float tanh_f(float x) {
  float e = __expf(-2.f * fabsf(x));
  float t = (1.f - e) * __builtin_amdgcn_rcpf(1.f + e);
  return x >= 0.f ? t : -t;
}

// Wave-level GEMM over one contiguous K-segment, batched B-loads.
// A (LDS, row-major, stride AS): rows (rt0+rt)*16+(lane&15), cols acol0+ks*32+quad*8
// W (global bf16, (N,Kw) row-major): rows wrow0+(lane&15), cols wk0+ks*32+quad*8
// D[m][n] += sum_k A[m][k]*W[n][k]  (act @ W.T)
template<int RT, int KS, int AS>
__device__ __forceinline__ void gemm_seg(f32x4 (&acc)[RT],
    const u16* __restrict__ W, const int Kw, const int wrow0, const int wk0,
    const u16* A, const int acol0, const int rt0, const int lane)
{
  const int n = lane & 15, quad = lane >> 4;
  bf16x8 b[KS];
  const u16* wp = W + (size_t)(wrow0 + n) * Kw + wk0 + quad * 8;
  #pragma unroll
  for (int ks = 0; ks < KS; ++ks)
    b[ks] = *reinterpret_cast<const bf16x8*>(wp + ks * 32);
  #pragma unroll
  for (int ks = 0; ks < KS; ++ks) {
    #pragma unroll
    for (int rt = 0; rt < RT; ++rt) {
      bf16x8 a = *reinterpret_cast<const bf16x8*>(A + ((rt0 + rt) * 16 + n) * AS + acol0 + ks * 32 + quad * 8);
      acc[rt] = __builtin_amdgcn_mfma_f32_16x16x32_bf16(a, b[ks], acc[rt], 0, 0, 0);
    }
  }
}

// bias + ReLU + bf16 store of D tiles to LDS
template<int RT, int DS>
__device__ __forceinline__ void store_relu(const f32x4 (&acc)[RT], u16* dst,
    const int col0, const int rt0, const float bias, const int lane)
{
  const int n = lane & 15, quad = lane >> 4;
  #pragma unroll
  for (int rt = 0; rt < RT; ++rt)
    #pragma unroll
    for (int i = 0; i < 4; ++i) {
      float v = fmaxf(acc[rt][i] + bias, 0.f);
      dst[((rt0 + rt) * 16 + quad * 4 + i) * DS + col0 + n] = f2bf(v);
    }
}

struct PrepArgs { const float* src[14]; int off[14]; int cnt[14]; };

__global__ void prep_weights(PrepArgs a, u16* __restrict__ dst) {
  const int j = blockIdx.y;
  const float* __restrict__ s = a.src[j];
  u16* d = dst + a.off[j];
  const int nel = a.cnt[j];
  for (int i = blockIdx.x * blockDim.x + threadIdx.x; i < nel; i += gridDim.x * blockDim.x)
    d[i] = f2bf(s[i]);
}

__global__ void zero_out_k(float* out) { if (threadIdx.x < 2) out[threadIdx.x] = 0.f; }

__global__ __launch_bounds__(NTHR, 4)
void vrnn_kernel(const float* __restrict__ states, const float* __restrict__ eps,
                 const float* __restrict__ enc_b1, const float* __restrict__ enc_b2,
                 const float* __restrict__ enc_mb, const float* __restrict__ enc_sb,
                 const float* __restrict__ pri_b1, const float* __restrict__ pri_b2,
                 const float* __restrict__ pri_mb, const float* __restrict__ pri_sb,
                 const float* __restrict__ dec_b1, const float* __restrict__ dec_b2,
                 const float* __restrict__ dec_mb, const float* __restrict__ dec_sb,
                 const float* __restrict__ gbih, const float* __restrict__ gbhh,
                 const u16* __restrict__ ws, float* __restrict__ out)
{
  __shared__ u16 cat[MROWS * CATS];    // [x|y|z|h] staging (48.5 KB)
  __shared__ u16 hb1[MROWS * HBS];     // layer-1 outputs; dec-heads alias cols 0-63 (32.5 KB)
  __shared__ u16 hb2[MROWS * HBS];     // layer-2 outputs (32.5 KB)
  __shared__ u16 hbhE[MROWS * HES];    // enc heads [em|softplus(es)] (16.5 KB)
  __shared__ u16 hbhP[MROWS * HES];    // pri heads [pm|softplus(ps)] (16.5 KB)

  const int tid = threadIdx.x;
  const int w = tid >> 6, lane = tid & 63;
  const int n = lane & 15, quad = lane >> 4;
  const int r0 = blockIdx.x * MROWS;
  const int n0 = w * 16;                         // wave's 16-col strip for N=256 layers
  const int cgE = w & 7, rtE0 = (w >> 3) * 2;    // enc/pri heads: 8 col-groups x 2 row-tile-pairs
  const int cgD = w & 3, rtD = w >> 2;           // dec heads: 4 col-groups x 4 row-tiles

  // ---- hoist loop-invariant bias scalars ----
  const int jW = n0 + n;
  const float b1e = enc_b1[jW], b2e = enc_b2[jW];
  const float b1p = pri_b1[jW], b2p = pri_b2[jW];
  const float b1d = dec_b1[jW], b2d = dec_b2[jW];
  const float brg = gbih[jW] + gbhh[jW];
  const float bug = gbih[RD + jW] + gbhh[RD + jW];
  const float bing = gbih[2 * RD + jW];
  const float bhng = gbhh[2 * RD + jW];
  const float bhE = (cgE < 4) ? enc_mb[cgE * 16 + n] : enc_sb[(cgE - 4) * 16 + n];
  const float bhP = (cgE < 4) ? pri_mb[cgE * 16 + n] : pri_sb[(cgE - 4) * 16 + n];
  const float bhD = (cgD < 2) ? dec_mb[cgD * 16 + n] : dec_sb[(cgD - 2) * 16 + n];

  // zero the h region of cat (h0 = 0)
  for (int i = tid; i < MROWS * (HD / 2); i += NTHR) {
    int row = i >> 7, c = (i & 127) * 2;
    *reinterpret_cast<u32*>(&cat[row * CATS + 128 + c]) = 0u;
  }

  float hreg[4][4];  // fp32 master h (C-layout of wave's 16-col strip, 4 row-tiles)
  #pragma unroll
  for (int a = 0; a < 4; ++a)
    #pragma unroll
    for (int c = 0; c < 4; ++c) hreg[a][c] = 0.f;

  // x/y staging: threads 0-511 own one float4 of x, 512-1023 one of y
  const int srow = (tid & 511) >> 3, sc4 = (tid & 7) * 4;
  f32x4 xyf = __builtin_nontemporal_load(
      reinterpret_cast<const f32x4*>(states + ((size_t)((tid < 512) ? 1 : 0) * BB + r0 + srow) * YD + sc4));

  // element-parallel maps
  const int mz = tid >> 4, jz = (tid & 15) * 4;  // z/KL: 64x64 as float4
  const int mn = tid >> 4, jn = (tid & 15) * 2;  // NLL: 64x32 as float2

  float kl_acc = 0.f, nll_acc = 0.f;

  for (int t = 0; t < TSTEPS; ++t) {
    // ---- P0: write prefetched x=states[t+1], y=states[t] into cat; issue scalar prefetches ----
    {
      u16* d = cat + srow * CATS + ((tid < 512) ? 0 : 32) + sc4;
      d[0] = f2bf(xyf.x); d[1] = f2bf(xyf.y); d[2] = f2bf(xyf.z); d[3] = f2bf(xyf.w);
    }
    f32x4 ev4 = __builtin_nontemporal_load(
        reinterpret_cast<const f32x4*>(eps + ((size_t)t * BB + r0 + mz) * ZD + jz));
    f32x2 xs2 = __builtin_nontemporal_load(
        reinterpret_cast<const f32x2*>(states + ((size_t)(t + 1) * BB + r0 + mn) * YD + jn));
    __syncthreads();

    // ---- P1: enc layer 1 [x,y,h] (K=320) -> hb1 ----
    {
      f32x4 acc[4] = {};
      gemm_seg<4, 2, CATS>(acc, ws + OFF_ENC_W1, 320, n0, 0, cat, 0, 0, lane);    // x,y
      gemm_seg<4, 8, CATS>(acc, ws + OFF_ENC_W1, 320, n0, 64, cat, 128, 0, lane); // h
      store_relu<4, HBS>(acc, hb1, n0, 0, b1e, lane);
    }
    __syncthreads();

    // ---- P2: enc layer 2 -> hb2 ----
    {
      f32x4 acc[4] = {};
      gemm_seg<4, 8, HBS>(acc, ws + OFF_ENC_W2, 256, n0, 0, hb1, 0, 0, lane);
      store_relu<4, HBS>(acc, hb2, n0, 0, b2e, lane);
    }
    __syncthreads();

    // ---- P3: enc heads -> hbhE (raw em | softplus es) ----
    {
      f32x4 acc[2] = {};
      gemm_seg<2, 8, HBS>(acc, ws + OFF_ENC_H, 256, cgE * 16, 0, hb2, 0, rtE0, lane);
      #pragma unroll
      for (int rt = 0; rt < 2; ++rt)
        #pragma unroll
        for (int i = 0; i < 4; ++i) {
          float v = acc[rt][i] + bhE;
          if (cgE >= 4) v = softplus_f(v);
          hbhE[((rtE0 + rt) * 16 + quad * 4 + i) * HES + cgE * 16 + n] = f2bf(v);
        }
    }
    __syncthreads();

    // ---- P4: z sample -> cat[z] (all threads, 4 elems) + pri layer 1 [y,h] -> hb1 ----
    {
      const float e4[4] = {ev4.x, ev4.y, ev4.z, ev4.w};
      #pragma unroll
      for (int c = 0; c < 4; ++c) {
        float em = bf2f(hbhE[mz * HES + jz + c]);
        float es = bf2f(hbhE[mz * HES + 64 + jz + c]);
        cat[mz * CATS + 64 + jz + c] = f2bf(em + es * e4[c]);
      }
      f32x4 acc[4] = {};
      gemm_seg<4, 1, CATS>(acc, ws + OFF_PRI_W1, 288, n0, 0, cat, 32, 0, lane);   // y
      gemm_seg<4, 8, CATS>(acc, ws + OFF_PRI_W1, 288, n0, 32, cat, 128, 0, lane); // h
      store_relu<4, HBS>(acc, hb1, n0, 0, b1p, lane);
    }
    __syncthreads();

    // ---- P5: pri layer 2 -> hb2 ----
    {
      f32x4 acc[4] = {};
      gemm_seg<4, 8, HBS>(acc, ws + OFF_PRI_W2, 256, n0, 0, hb1, 0, 0, lane);
      store_relu<4, HBS>(acc, hb2, n0, 0, b2p, lane);
    }
    __syncthreads();

    // ---- P6: pri heads -> hbhP ----
    {
      f32x4 acc[2] = {};
      gemm_seg<2, 8, HBS>(acc, ws + OFF_PRI_H, 256, cgE * 16, 0, hb2, 0, rtE0, lane);
      #pragma unroll
      for (int rt = 0; rt < 2; ++rt)
        #pragma unroll
        for (int i = 0; i < 4; ++i) {
          float v = acc[rt][i] + bhP;
          if (cgE >= 4) v = softplus_f(v);
          hbhP[((rtE0 + rt) * 16 + quad * 4 + i) * HES + cgE * 16 + n] = f2bf(v);
        }
    }
    __syncthreads();

    // ---- P7: KL (all threads, 4 elems) + dec layer 1 [y,z,h] -> hb1 ----
    {
      #pragma unroll
      for (int c = 0; c < 4; ++c) {
        float em = bf2f(hbhE[mz * HES + jz + c]);
        float es = bf2f(hbhE[mz * HES + 64 + jz + c]);
        float pm = bf2f(hbhP[mz * HES + jz + c]);
        float ps = bf2f(hbhP[mz * HES + 64 + jz + c]);
        float d = em - pm;
        kl_acc += 0.5f * (2.f * __logf(ps * __builtin_amdgcn_rcpf(es))
                          + (es * es + d * d) / (ps * ps) - 1.f);
      }
      f32x4 acc[4] = {};
      gemm_seg<4, 3, CATS>(acc, ws + OFF_DEC_W1, 352, n0, 0, cat, 32, 0, lane);   // y,z
      gemm_seg<4, 8, CATS>(acc, ws + OFF_DEC_W1, 352, n0, 96, cat, 128, 0, lane); // h
      store_relu<4, HBS>(acc, hb1, n0, 0, b1d, lane);
    }
    __syncthreads();

    // ---- P8: dec layer 2 -> hb2 ----
    {
      f32x4 acc[4] = {};
      gemm_seg<4, 8, HBS>(acc, ws + OFF_DEC_W2, 256, n0, 0, hb1, 0, 0, lane);
      store_relu<4, HBS>(acc, hb2, n0, 0, b2d, lane);
    }
    __syncthreads();

    // ---- P9: dec heads (all 16 waves) -> hb1-alias cols 0-63; GRU gemms + gates ----
    {
      {
        f32x4 acc[1] = {};
        gemm_seg<1, 8, HBS>(acc, ws + OFF_DEC_H, 256, cgD * 16, 0, hb2, 0, rtD, lane);
        #pragma unroll
        for (int i = 0; i < 4; ++i) {
          float v = acc[0][i] + bhD;
          if (cgD >= 2) v = softplus_f(v);
          hb1[(rtD * 16 + quad * 4 + i) * HBS + cgD * 16 + n] = f2bf(v);
        }
      }
      // GRU (torch gate order r,z,n), staged:
      f32x4 aH[4] = {};
      gemm_seg<4, 8, CATS>(aH, ws + OFF_GWHH, 256, 2 * RD + n0, 0, cat, 128, 0, lane);
      {
        f32x4 aR[4] = {};
        gemm_seg<4, 1, CATS>(aR, ws + OFF_GWIH, 96, n0, 0, cat, 0, 0, lane);       // x
        gemm_seg<4, 2, CATS>(aR, ws + OFF_GWIH, 96, n0, 32, cat, 64, 0, lane);     // z
        gemm_seg<4, 8, CATS>(aR, ws + OFF_GWHH, 256, n0, 0, cat, 128, 0, lane);    // h
        #pragma unroll
        for (int rt = 0; rt < 4; ++rt)
          #pragma unroll
          for (int i = 0; i < 4; ++i)
            aH[rt][i] = sigmoid_f(aR[rt][i] + brg) * (aH[rt][i] + bhng);
      }
      {
        f32x4 aN[4] = {};
        gemm_seg<4, 1, CATS>(aN, ws + OFF_GWIH, 96, 2 * RD + n0, 0, cat, 0, 0, lane);
        gemm_seg<4, 2, CATS>(aN, ws + OFF_GWIH, 96, 2 * RD + n0, 32, cat, 64, 0, lane);
        #pragma unroll
        for (int rt = 0; rt < 4; ++rt)
          #pragma unroll
          for (int i = 0; i < 4; ++i)
            aH[rt][i] = tanh_f(aN[rt][i] + bing + aH[rt][i]);  // aH now holds n
      }
      {
        f32x4 aU[4] = {};
        gemm_seg<4, 1, CATS>(aU, ws + OFF_GWIH, 96, RD + n0, 0, cat, 0, 0, lane);
        gemm_seg<4, 2, CATS>(aU, ws + OFF_GWIH, 96, RD + n0, 32, cat, 64, 0, lane);
        gemm_seg<4, 8, CATS>(aU, ws + OFF_GWHH, 256, RD + n0, 0, cat, 128, 0, lane);
        #pragma unroll
        for (int rt = 0; rt < 4; ++rt)
          #pragma unroll
          for (int i = 0; i < 4; ++i) {
            float u = sigmoid_f(aU[rt][i] + bug);
            hreg[rt][i] = (1.f - u) * aH[rt][i] + u * hreg[rt][i];
          }
      }
      // prefetch next step's x/y float4
      const int tn = (t + 1 < TSTEPS) ? t + 1 : TSTEPS - 1;
      xyf = __builtin_nontemporal_load(
          reinterpret_cast<const f32x4*>(states + ((size_t)((tid < 512) ? tn + 1 : tn) * BB + r0 + srow) * YD + sc4));
    }
    __syncthreads();

    // ---- P10: NLL (all threads) + write h_new -> cat[h] ----
    {
      const float x2[2] = {xs2.x, xs2.y};
      #pragma unroll
      for (int c = 0; c < 2; ++c) {
        float dm = bf2f(hb1[mn * HBS + jn + c]);
        float ds = bf2f(hb1[mn * HBS + 32 + jn + c]);
        float dd = x2[c] - dm;
        nll_acc += __logf(ds) + dd * dd / (2.f * ds * ds) + 0.91893853320467274178f;
      }
    }
    #pragma unroll
    for (int rt = 0; rt < 4; ++rt)
      #pragma unroll
      for (int i = 0; i < 4; ++i)
        cat[(rt * 16 + quad * 4 + i) * CATS + 128 + n0 + n] = f2bf(hreg[rt][i]);
    // no barrier: P0's barrier orders h/x/y/z writes before next step's reads;
    // hb1-alias read here is ordered vs P1's hb1 write by P0's barrier too.
  }

  // ---- final reduction: wave shuffle + one atomic per wave ----
  float kv = kl_acc, nv = nll_acc;
  #pragma unroll
  for (int off = 32; off > 0; off >>= 1) {
    kv += __shfl_down(kv, off, 64);
    nv += __shfl_down(nv, off, 64);
  }
  if (lane == 0) {
    atomicAdd(out + 0, kv);
    atomicAdd(out + 1, nv);
  }
}

extern "C" void kernel_launch(void* const* d_in, const int* in_sizes, int n_in,
                              void* d_out, int out_size, void* d_ws, size_t ws_size,
                              hipStream_t stream) {
  const float* states = (const float*)d_in[0];
  const float* eps    = (const float*)d_in[1];
  u16* ws   = (u16*)d_ws;
  float* out = (float*)d_out;

  PrepArgs pa;
  const int jsrc[14] = {2, 4, 6, 8, 10, 12, 14, 16, 18, 20, 22, 24, 26, 27};
  const int joff[14] = {OFF_ENC_W1, OFF_ENC_W2, OFF_ENC_H, OFF_ENC_H + 16384,
                        OFF_PRI_W1, OFF_PRI_W2, OFF_PRI_H, OFF_PRI_H + 16384,
                        OFF_DEC_W1, OFF_DEC_W2, OFF_DEC_H, OFF_DEC_H + 8192,
                        OFF_GWIH, OFF_GWHH};
  const int jcnt[14] = {81920, 65536, 16384, 16384,
                        73728, 65536, 16384, 16384,
                        90112, 65536, 8192, 8192,
                        73728, 196608};
  for (int j = 0; j < 14; ++j) {
    pa.src[j] = (const float*)d_in[jsrc[j]];
    pa.off[j] = joff[j];
    pa.cnt[j] = jcnt[j];
  }

  zero_out_k<<<dim3(1), dim3(64), 0, stream>>>(out);
  prep_weights<<<dim3(64, 14), dim3(256), 0, stream>>>(pa, ws);
  vrnn_kernel<<<dim3(NBLK), dim3(NTHR), 0, stream>>>(
      states, eps,
      (const float*)d_in[3],  (const float*)d_in[5],
      (const float*)d_in[7],  (const float*)d_in[9],
      (const float*)d_in[11], (const float*)d_in[13],
      (const float*)d_in[15], (const float*)d_in[17],
      (const float*)d_in[19], (const float*)d_in[21],
      (const float*)d_in[23], (const float*)d_in[25],
      (const float*)d_in[28], (const float*)d_in[29],
      ws, out);
}